// Round 2
// baseline (104.419 us; speedup 1.0000x reference)
//
#include <hip/hip_runtime.h>

// Chamfer loss: pred/target [B=4, 3, N=8192] f32, channel-first.
// d2(n,m) = p2[n] + t2[m] - 2*dot(p[n], t[m])
// Kernel 1: per (dir, batch, n-chunk, m-chunk) block computes
//   partial[n] = p2[n] + min_{m in chunk} (t2[m] - 2*cross)
// Kernel 2: min over m-chunks, sqrt, mean, sum both directions.

constexpr int NPTS   = 8192;
constexpr int BATCH  = 4;
constexpr int BLK    = 256;
constexpr int PPT    = 8;                    // A-points per thread
constexpr int MSPLIT = 16;                   // M-chunks (parallelism)
constexpr int MCH    = NPTS / MSPLIT;        // 512 m-points per block
constexpr int NCHUNK = NPTS / (BLK * PPT);   // 4 n-chunks

__global__ __launch_bounds__(BLK) void chamfer_partial(
    const float* __restrict__ pred, const float* __restrict__ targ,
    float* __restrict__ ws)
{
    __shared__ float4 tile[MCH];   // (-2tx, -2ty, -2tz, t2) per staged point

    const int bz  = blockIdx.z;          // b*2 + dir
    const int dir = bz & 1;
    const int b   = bz >> 1;
    const int ms  = blockIdx.y;          // which m-chunk
    const int nc  = blockIdx.x;          // which n-chunk

    const float* A  = dir ? targ : pred;
    const float* Bp = dir ? pred : targ;
    const float* Ab = A  + (size_t)b * 3 * NPTS;
    const float* Bb = Bp + (size_t)b * 3 * NPTS;

    // ---- stage m-chunk into LDS (coalesced, 512 pts, 8 KB) ----
    const int m0 = ms * MCH;
    for (int i = threadIdx.x; i < MCH; i += BLK) {
        float tx = Bb[m0 + i];
        float ty = Bb[NPTS + m0 + i];
        float tz = Bb[2 * NPTS + m0 + i];
        tile[i] = make_float4(-2.f * tx, -2.f * ty, -2.f * tz,
                              tx * tx + ty * ty + tz * tz);
    }

    // ---- my PPT A-points (coalesced: n = n0 + k*BLK) ----
    const int n0 = nc * (BLK * PPT) + threadIdx.x;
    float px[PPT], py[PPT], pz[PPT], p2[PPT], vmin[PPT];
    #pragma unroll
    for (int k = 0; k < PPT; ++k) {
        int n = n0 + k * BLK;
        px[k] = Ab[n];
        py[k] = Ab[NPTS + n];
        pz[k] = Ab[2 * NPTS + n];
        p2[k] = px[k] * px[k] + py[k] * py[k] + pz[k] * pz[k];
        vmin[k] = 3.4e38f;
    }

    __syncthreads();

    // ---- hot loop: 1 broadcast b128 read feeds 8x(3 FMA + min) ----
    #pragma unroll 4
    for (int mm = 0; mm < MCH; ++mm) {
        float4 q = tile[mm];
        #pragma unroll
        for (int k = 0; k < PPT; ++k) {
            float v = fmaf(q.x, px[k], fmaf(q.y, py[k], fmaf(q.z, pz[k], q.w)));
            vmin[k] = fminf(vmin[k], v);
        }
    }

    // ---- partial d2 -> ws[(dir*MSPLIT+ms)][b*NPTS + n] ----
    float* wsd = ws + (size_t)(dir * MSPLIT + ms) * (BATCH * NPTS)
                    + (size_t)b * NPTS;
    #pragma unroll
    for (int k = 0; k < PPT; ++k) {
        wsd[n0 + k * BLK] = p2[k] + vmin[k];
    }
}

__global__ __launch_bounds__(BLK) void chamfer_reduce(
    const float* __restrict__ ws, float* __restrict__ out)
{
    const int i   = blockIdx.x * BLK + threadIdx.x;   // 0..65535
    const int dir = i >> 15;
    const int pt  = i & 32767;                        // b*NPTS + n

    float v = 3.4e38f;
    #pragma unroll
    for (int ms = 0; ms < MSPLIT; ++ms)
        v = fminf(v, ws[(size_t)(dir * MSPLIT + ms) * (BATCH * NPTS) + pt]);

    float d = sqrtf(fmaxf(v, 0.f)) * (1.0f / (BATCH * NPTS));

    // wave (64) reduce, then block reduce, one atomic per block
    for (int off = 32; off > 0; off >>= 1)
        d += __shfl_down(d, off);

    __shared__ float wsum[BLK / 64];
    if ((threadIdx.x & 63) == 0) wsum[threadIdx.x >> 6] = d;
    __syncthreads();
    if (threadIdx.x == 0) {
        float s = 0.f;
        #pragma unroll
        for (int w = 0; w < BLK / 64; ++w) s += wsum[w];
        atomicAdd(out, s);
    }
}

extern "C" void kernel_launch(void* const* d_in, const int* in_sizes, int n_in,
                              void* d_out, int out_size, void* d_ws, size_t ws_size,
                              hipStream_t stream) {
    const float* pred = (const float*)d_in[0];
    const float* targ = (const float*)d_in[1];
    float* out = (float*)d_out;
    float* ws  = (float*)d_ws;   // needs 2*MSPLIT*BATCH*NPTS*4 = 4 MB

    // d_out is re-poisoned to 0xAA before every launch; zero it async
    // (graph-capture-safe) since chamfer_reduce accumulates via atomicAdd.
    hipMemsetAsync(d_out, 0, sizeof(float), stream);

    dim3 grid(NCHUNK, MSPLIT, BATCH * 2);   // 4 x 16 x 8 = 512 blocks
    chamfer_partial<<<grid, BLK, 0, stream>>>(pred, targ, ws);

    chamfer_reduce<<<(2 * BATCH * NPTS) / BLK, BLK, 0, stream>>>(ws, out);
}

// Round 3
// 102.106 us; speedup vs baseline: 1.0227x; 1.0227x over previous
//
#include <hip/hip_runtime.h>

// Chamfer loss via MFMA: d2(n,m) = sum_k A[n][k]*B[k][m] with K=16 bf16
// hi/lo-split packing (~f32 precision). One 32x32x16 bf16 MFMA = 32x32 d2 tile.
// Row-min (pred->target) accumulates in registers; col-min (target->pred)
// via in-register tree + lane swap + LDS atomicMin; partials to ws.

typedef __attribute__((ext_vector_type(8)))  short bf16x8;
typedef __attribute__((ext_vector_type(16))) float f32x16;

constexpr int NPTS    = 8192;
constexpr int BATCH   = 4;
constexpr int NB_ROWS = 128;               // rows per block (4 waves x 32)
constexpr int N_NB    = NPTS / NB_ROWS;    // 64 n-blocks per batch
constexpr int HALF_M  = NPTS / 2;          // 4096 (m-half per block)
constexpr int STEPS   = HALF_M / 32;       // 128 m-steps per wave
constexpr int GROUPS  = STEPS / 4;         // 32 groups of 4 steps

// ws layout (bytes):
//   [0, 1MB)          B-table: BATCH*NPTS*32
//   [1MB, +256KB)     ws_row : BATCH*2*NPTS f32   (per m-half row-min partials)
//   [1.25MB, +8MB)    ws_col : BATCH*N_NB*NPTS f32-bits-as-int (col-min partials)
constexpr size_t WS_ROW_OFF = (size_t)BATCH * NPTS * 32;
constexpr size_t WS_COL_OFF = WS_ROW_OFF + (size_t)BATCH * 2 * NPTS * 4;
// total ws needed: 9.25 MB

__device__ inline unsigned short f2bf(float x) {          // RNE f32->bf16
    unsigned u = __float_as_uint(x);
    u += 0x7FFFu + ((u >> 16) & 1u);
    return (unsigned short)(u >> 16);
}
__device__ inline float bf2f(unsigned short h) {
    return __uint_as_float(((unsigned)h) << 16);
}

// ---------------- pack target-side K=16 table ----------------
__global__ __launch_bounds__(256) void pack_b(const float* __restrict__ targ,
                                              unsigned int* __restrict__ wsb) {
    int tid = blockIdx.x * 256 + threadIdx.x;          // 0..32767
    int b = tid >> 13, m = tid & (NPTS - 1);
    const float* tb = targ + (size_t)b * 3 * NPTS;
    float tx = tb[m], ty = tb[NPTS + m], tz = tb[2 * NPTS + m];
    float t2 = fmaf(tx, tx, fmaf(ty, ty, tz * tz));
    unsigned short xh = f2bf(tx), yh = f2bf(ty), zh = f2bf(tz);
    unsigned short xl = f2bf(tx - bf2f(xh));
    unsigned short yl = f2bf(ty - bf2f(yh));
    unsigned short zl = f2bf(tz - bf2f(zh));
    unsigned short t2h = f2bf(t2), t2l = f2bf(t2 - bf2f(t2h));
    const unsigned short ONE = 0x3F80;
    // k: 0:1*p2h 1:1*p2l 2:t2h*1 3:t2l*1 4:txh 5:txl 6:txh 7:tyh
    //    8:tyl 9:tyh 10:tzh 11:tzl 12:tzh 13-15:0
    unsigned int u0 = (unsigned)ONE | ((unsigned)ONE << 16);
    unsigned int u1 = (unsigned)t2h | ((unsigned)t2l << 16);
    unsigned int u2 = (unsigned)xh  | ((unsigned)xl  << 16);
    unsigned int u3 = (unsigned)xh  | ((unsigned)yh  << 16);
    unsigned int u4 = (unsigned)yl  | ((unsigned)yh  << 16);
    unsigned int u5 = (unsigned)zh  | ((unsigned)zl  << 16);
    unsigned int u6 = (unsigned)zh;
    uint4 lo = make_uint4(u0, u1, u2, u3);
    uint4 hi = make_uint4(u4, u5, u6, 0u);
    uint4* dst = (uint4*)wsb;
    dst[(size_t)tid * 2]     = lo;
    dst[(size_t)tid * 2 + 1] = hi;
}

// ---------------- main MFMA kernel ----------------
__global__ __launch_bounds__(256) void chamfer_mfma(
    const float* __restrict__ pred, const unsigned int* __restrict__ wsb,
    float* __restrict__ ws_row, int* __restrict__ ws_col) {
    __shared__ int colpart[HALF_M];   // 16 KB, float-bits as int

    const int tid  = threadIdx.x;
    const int lane = tid & 63;
    const int wv   = tid >> 6;        // stripe 0..3
    const int nb   = blockIdx.x;      // 0..63
    const int half = blockIdx.y;      // 0..1
    const int b    = blockIdx.z;      // 0..3

    for (int i = tid; i < HALF_M; i += 256) colpart[i] = 0x7F800000;

    // ---- build A fragment (once): 32 rows x K=16, lane row = lane&31 ----
    const int row = nb * NB_ROWS + wv * 32 + (lane & 31);
    const int g   = lane >> 5;        // k-group
    const float* pb = pred + (size_t)b * 3 * NPTS;
    float px = pb[row], py = pb[NPTS + row], pz = pb[2 * NPTS + row];
    float p2 = fmaf(px, px, fmaf(py, py, pz * pz));
    unsigned short xh = f2bf(px), yh = f2bf(py), zh = f2bf(pz);
    unsigned short xl = f2bf(px - bf2f(xh));
    unsigned short yl = f2bf(py - bf2f(yh));
    unsigned short zl = f2bf(pz - bf2f(zh));
    unsigned short p2h = f2bf(p2), p2l = f2bf(p2 - bf2f(p2h));
    unsigned short mxh = f2bf(-2.f * bf2f(xh)), mxl = f2bf(-2.f * bf2f(xl));
    unsigned short myh = f2bf(-2.f * bf2f(yh)), myl = f2bf(-2.f * bf2f(yl));
    unsigned short mzh = f2bf(-2.f * bf2f(zh)), mzl = f2bf(-2.f * bf2f(zl));
    const unsigned short ONE = 0x3F80;
    unsigned short av[8];
    if (g == 0) {
        av[0]=p2h; av[1]=p2l; av[2]=ONE; av[3]=ONE;
        av[4]=mxh; av[5]=mxh; av[6]=mxl; av[7]=myh;
    } else {
        av[0]=myh; av[1]=myl; av[2]=mzh; av[3]=mzh;
        av[4]=mzl; av[5]=0;   av[6]=0;   av[7]=0;
    }
    bf16x8 af;
    #pragma unroll
    for (int i = 0; i < 8; ++i) af[i] = (short)av[i];

    f32x16 zero;
    #pragma unroll
    for (int i = 0; i < 16; ++i) zero[i] = 0.f;

    float rowacc[16];
    #pragma unroll
    for (int i = 0; i < 16; ++i) rowacc[i] = __int_as_float(0x7F800000);

    // B-frag byte address for step s: btab + s*1024
    const char* btab = (const char*)wsb
        + ((size_t)b * NPTS + (size_t)half * HALF_M) * 32
        + (size_t)(lane & 31) * 32 + (size_t)g * 16;

    auto ldg = [&](int s) -> bf16x8 {
        return *reinterpret_cast<const bf16x8*>(btab + (size_t)s * 1024);
    };

    __syncthreads();

    auto proc = [&](bf16x8 bf, int s) {
        f32x16 c = __builtin_amdgcn_mfma_f32_32x32x16_bf16(af, bf, zero, 0, 0, 0);
        #pragma unroll
        for (int i = 0; i < 16; ++i) rowacc[i] = fminf(rowacc[i], c[i]);
        float t0 = fminf(fminf(c[0], c[1]),  c[2]);
        float t1 = fminf(fminf(c[3], c[4]),  c[5]);
        float t2 = fminf(fminf(c[6], c[7]),  c[8]);
        float t3 = fminf(fminf(c[9], c[10]), c[11]);
        float t4 = fminf(fminf(c[12], c[13]), c[14]);
        float colv = fminf(fminf(fminf(t0, t1), t2), fminf(fminf(t3, t4), c[15]));
        colv = fminf(colv, __shfl_xor(colv, 32));
        if (lane < 32) atomicMin(&colpart[s * 32 + lane], __float_as_int(colv));
    };

    // ---- ping-pong pipeline: 4-step groups, prefetch next group ----
    bf16x8 A0 = ldg(0), A1 = ldg(1), A2 = ldg(2), A3 = ldg(3);
    bf16x8 B0, B1, B2, B3;
    for (int gp = 0; gp < GROUPS - 1; gp += 2) {
        const int s1 = (gp + 1) * 4;
        B0 = ldg(s1); B1 = ldg(s1 + 1); B2 = ldg(s1 + 2); B3 = ldg(s1 + 3);
        const int s0 = gp * 4;
        proc(A0, s0); proc(A1, s0 + 1); proc(A2, s0 + 2); proc(A3, s0 + 3);
        if (gp + 2 < GROUPS) {
            const int s2 = (gp + 2) * 4;
            A0 = ldg(s2); A1 = ldg(s2 + 1); A2 = ldg(s2 + 2); A3 = ldg(s2 + 3);
        }
        proc(B0, s1); proc(B1, s1 + 1); proc(B2, s1 + 2); proc(B3, s1 + 3);
    }

    // ---- finalize rows: butterfly min over the 32 col-lanes ----
    #pragma unroll
    for (int i = 0; i < 16; ++i) {
        float v = rowacc[i];
        v = fminf(v, __shfl_xor(v, 1));
        v = fminf(v, __shfl_xor(v, 2));
        v = fminf(v, __shfl_xor(v, 4));
        v = fminf(v, __shfl_xor(v, 8));
        v = fminf(v, __shfl_xor(v, 16));
        rowacc[i] = v;
    }
    if ((lane & 31) == 0) {
        #pragma unroll
        for (int i = 0; i < 16; ++i) {
            int r = (i & 3) + 8 * (i >> 2) + 4 * g;   // C/D row map (m74/m101)
            ws_row[((size_t)b * 2 + half) * NPTS + nb * NB_ROWS + wv * 32 + r] =
                rowacc[i];
        }
    }

    __syncthreads();
    int* dstc = ws_col + ((size_t)(b * N_NB + nb)) * NPTS + (size_t)half * HALF_M;
    for (int i = tid; i < HALF_M; i += 256) dstc[i] = colpart[i];
}

// ---------------- final reduce ----------------
__global__ __launch_bounds__(256) void reduce_k(const float* __restrict__ ws_row,
                                                const int* __restrict__ ws_col,
                                                float* __restrict__ out) {
    int tid = blockIdx.x * 256 + threadIdx.x;   // 0..32767
    int b = tid >> 13, m = tid & (NPTS - 1);
    float cv = __int_as_float(0x7F800000);
    const int* base = ws_col + (size_t)b * N_NB * NPTS + m;
    #pragma unroll 8
    for (int nb = 0; nb < N_NB; ++nb)
        cv = fminf(cv, __int_as_float(base[(size_t)nb * NPTS]));
    float rv = fminf(ws_row[((size_t)b * 2) * NPTS + m],
                     ws_row[((size_t)b * 2 + 1) * NPTS + m]);
    float d = sqrtf(fmaxf(cv, 0.f)) + sqrtf(fmaxf(rv, 0.f));
    d *= (1.0f / 32768.0f);
    for (int off = 32; off; off >>= 1) d += __shfl_down(d, off);
    __shared__ float wsum[4];
    if ((threadIdx.x & 63) == 0) wsum[threadIdx.x >> 6] = d;
    __syncthreads();
    if (threadIdx.x == 0) atomicAdd(out, wsum[0] + wsum[1] + wsum[2] + wsum[3]);
}

extern "C" void kernel_launch(void* const* d_in, const int* in_sizes, int n_in,
                              void* d_out, int out_size, void* d_ws, size_t ws_size,
                              hipStream_t stream) {
    const float* pred = (const float*)d_in[0];
    const float* targ = (const float*)d_in[1];
    float* out = (float*)d_out;
    char* ws = (char*)d_ws;

    unsigned int* wsb = (unsigned int*)ws;
    float* ws_row = (float*)(ws + WS_ROW_OFF);
    int*   ws_col = (int*)(ws + WS_COL_OFF);

    hipMemsetAsync(d_out, 0, sizeof(float), stream);

    pack_b<<<(BATCH * NPTS) / 256, 256, 0, stream>>>(targ, wsb);

    dim3 grid(N_NB, 2, BATCH);   // 64 x 2 x 4 = 512 blocks
    chamfer_mfma<<<grid, 256, 0, stream>>>(pred, wsb, ws_row, ws_col);

    reduce_k<<<(2 * BATCH * NPTS) / 512, 256, 0, stream>>>(ws_row, ws_col, out);
}

// Round 6
// 90.550 us; speedup vs baseline: 1.1532x; 1.1276x over previous
//
#include <hip/hip_runtime.h>

// Chamfer loss via MFMA, two-pass (one per direction), register-only epilogue.
// d2(n,m) = sum_k A[n][k]*B[k][m], K=16 bf16 hi/lo-split packing (~f32 precise).
// Each block: 128 rows (4 waves x 32) of one (batch, dir), sweeps all 8192 cols.
// Row-min accumulates in registers (v_min3 pairs); finalize = lane butterfly +
// sqrt + one atomicAdd per block. No col-min path, no reduce kernel.

typedef __attribute__((ext_vector_type(8)))  short bf16x8;
typedef __attribute__((ext_vector_type(16))) float f32x16;

constexpr int NPTS    = 8192;
constexpr int BATCH   = 4;
constexpr int NB_ROWS = 128;               // rows per block (4 waves x 32)
constexpr int N_NB    = NPTS / NB_ROWS;    // 64 row-blocks per (batch,dir)
constexpr int STEPS   = NPTS / 32;         // 256 col-steps per wave

// ws: [0, 1MB) packed targ table; [1MB, 2MB) packed pred table. 32 B/point.
constexpr size_t TBL_BYTES = (size_t)BATCH * NPTS * 32;

__device__ inline unsigned short f2bf(float x) {          // RNE f32->bf16
    unsigned u = __float_as_uint(x);
    u += 0x7FFFu + ((u >> 16) & 1u);
    return (unsigned short)(u >> 16);
}
__device__ inline float bf2f(unsigned short h) {
    return __uint_as_float(((unsigned)h) << 16);
}

// ---------------- pack both point sets into B-operand tables ----------------
__global__ __launch_bounds__(256) void pack_both(
    const float* __restrict__ pred, const float* __restrict__ targ,
    unsigned int* __restrict__ wsb) {
    int tid = blockIdx.x * 256 + threadIdx.x;          // 0..65535
    int which = tid >> 15;                             // 0: targ, 1: pred
    int r = tid & 32767;
    int b = r >> 13, m = r & (NPTS - 1);
    const float* src = which ? pred : targ;
    const float* tb = src + (size_t)b * 3 * NPTS;
    float tx = tb[m], ty = tb[NPTS + m], tz = tb[2 * NPTS + m];
    float t2 = fmaf(tx, tx, fmaf(ty, ty, tz * tz));
    unsigned short xh = f2bf(tx), yh = f2bf(ty), zh = f2bf(tz);
    unsigned short xl = f2bf(tx - bf2f(xh));
    unsigned short yl = f2bf(ty - bf2f(yh));
    unsigned short zl = f2bf(tz - bf2f(zh));
    unsigned short t2h = f2bf(t2), t2l = f2bf(t2 - bf2f(t2h));
    const unsigned short ONE = 0x3F80;
    // k: 0:1*p2h 1:1*p2l 2:t2h*1 3:t2l*1 4:txh 5:txl 6:txh 7:tyh
    //    8:tyl 9:tyh 10:tzh 11:tzl 12:tzh 13-15:0   (pairs A round-3-verified)
    unsigned int u0 = (unsigned)ONE | ((unsigned)ONE << 16);
    unsigned int u1 = (unsigned)t2h | ((unsigned)t2l << 16);
    unsigned int u2 = (unsigned)xh  | ((unsigned)xl  << 16);
    unsigned int u3 = (unsigned)xh  | ((unsigned)yh  << 16);
    unsigned int u4 = (unsigned)yl  | ((unsigned)yh  << 16);
    unsigned int u5 = (unsigned)zh  | ((unsigned)zl  << 16);
    unsigned int u6 = (unsigned)zh;
    uint4* dst = (uint4*)wsb;
    dst[(size_t)tid * 2]     = make_uint4(u0, u1, u2, u3);
    dst[(size_t)tid * 2 + 1] = make_uint4(u4, u5, u6, 0u);
}

// ---------------- main kernel: both directions, row-min only ----------------
__global__ __launch_bounds__(256) void chamfer_both(
    const float* __restrict__ pred, const float* __restrict__ targ,
    const unsigned int* __restrict__ wsb, float* __restrict__ out) {
    const int tid  = threadIdx.x;
    const int lane = tid & 63;
    const int wv   = tid >> 6;
    const int nb   = blockIdx.x;      // 0..63 row-block
    const int dir  = blockIdx.y;      // 0: pred->targ, 1: targ->pred
    const int b    = blockIdx.z;      // batch

    // A-side: raw coords of the "query" set, packed in-register (round-3 scheme)
    const float* rowsrc = dir ? targ : pred;
    const int row = nb * NB_ROWS + wv * 32 + (lane & 31);
    const int g   = lane >> 5;        // k-group
    const float* pb = rowsrc + (size_t)b * 3 * NPTS;
    float px = pb[row], py = pb[NPTS + row], pz = pb[2 * NPTS + row];
    float p2 = fmaf(px, px, fmaf(py, py, pz * pz));
    unsigned short xh = f2bf(px), yh = f2bf(py), zh = f2bf(pz);
    unsigned short xl = f2bf(px - bf2f(xh));
    unsigned short yl = f2bf(py - bf2f(yh));
    unsigned short zl = f2bf(pz - bf2f(zh));
    unsigned short p2h = f2bf(p2), p2l = f2bf(p2 - bf2f(p2h));
    unsigned short mxh = f2bf(-2.f * bf2f(xh)), mxl = f2bf(-2.f * bf2f(xl));
    unsigned short myh = f2bf(-2.f * bf2f(yh)), myl = f2bf(-2.f * bf2f(yl));
    unsigned short mzh = f2bf(-2.f * bf2f(zh)), mzl = f2bf(-2.f * bf2f(zl));
    const unsigned short ONE = 0x3F80;
    unsigned short av[8];
    if (g == 0) {
        av[0]=p2h; av[1]=p2l; av[2]=ONE; av[3]=ONE;
        av[4]=mxh; av[5]=mxh; av[6]=mxl; av[7]=myh;
    } else {
        av[0]=myh; av[1]=myl; av[2]=mzh; av[3]=mzh;
        av[4]=mzl; av[5]=0;   av[6]=0;   av[7]=0;
    }
    bf16x8 af;
    #pragma unroll
    for (int i = 0; i < 8; ++i) af[i] = (short)av[i];

    f32x16 zero;
    #pragma unroll
    for (int i = 0; i < 16; ++i) zero[i] = 0.f;

    float racc[16];
    #pragma unroll
    for (int i = 0; i < 16; ++i) racc[i] = __int_as_float(0x7F800000);

    // B-side: packed table of the "database" set (targ for dir0, pred for dir1)
    const char* btab = (const char*)wsb
        + (size_t)dir * TBL_BYTES
        + (size_t)b * NPTS * 32
        + (size_t)(lane & 31) * 32 + (size_t)g * 16;

    auto ldg = [&](int s) -> bf16x8 {
        return *reinterpret_cast<const bf16x8*>(btab + (size_t)s * 1024);
    };
    auto step2 = [&](bf16x8 f0, bf16x8 f1) {
        f32x16 c0 = __builtin_amdgcn_mfma_f32_32x32x16_bf16(af, f0, zero, 0, 0, 0);
        f32x16 c1 = __builtin_amdgcn_mfma_f32_32x32x16_bf16(af, f1, zero, 0, 0, 0);
        #pragma unroll
        for (int i = 0; i < 16; ++i)
            racc[i] = fminf(fminf(racc[i], c0[i]), c1[i]);   // -> v_min3_f32
    };

    // 4-step groups with next-group prefetch
    bf16x8 f0 = ldg(0), f1 = ldg(1), f2 = ldg(2), f3 = ldg(3);
    for (int s = 0; s < STEPS - 4; s += 4) {
        bf16x8 n0 = ldg(s + 4), n1 = ldg(s + 5), n2 = ldg(s + 6), n3 = ldg(s + 7);
        step2(f0, f1);
        step2(f2, f3);
        f0 = n0; f1 = n1; f2 = n2; f3 = n3;
    }
    step2(f0, f1);
    step2(f2, f3);

    // ---- finalize: butterfly min over the 32 col-lanes (halves separate) ----
    float s = 0.f;
    #pragma unroll
    for (int i = 0; i < 16; ++i) {
        float v = racc[i];
        v = fminf(v, __shfl_xor(v, 1));
        v = fminf(v, __shfl_xor(v, 2));
        v = fminf(v, __shfl_xor(v, 4));
        v = fminf(v, __shfl_xor(v, 8));
        v = fminf(v, __shfl_xor(v, 16));
        s += sqrtf(fmaxf(v, 0.f));   // per-row sqrt; rows differ by g via layout
    }
    s += __shfl_xor(s, 32);          // add the other k-group-half's 16 rows

    __shared__ float wsum[4];
    if (lane == 0) wsum[wv] = s;
    __syncthreads();
    if (tid == 0)
        atomicAdd(out, (wsum[0] + wsum[1] + wsum[2] + wsum[3]) * (1.0f / 32768.0f));
}

extern "C" void kernel_launch(void* const* d_in, const int* in_sizes, int n_in,
                              void* d_out, int out_size, void* d_ws, size_t ws_size,
                              hipStream_t stream) {
    const float* pred = (const float*)d_in[0];
    const float* targ = (const float*)d_in[1];
    float* out = (float*)d_out;
    unsigned int* wsb = (unsigned int*)d_ws;   // 2 MB used

    hipMemsetAsync(d_out, 0, sizeof(float), stream);

    pack_both<<<(2 * BATCH * NPTS) / 256, 256, 0, stream>>>(pred, targ, wsb);

    dim3 grid(N_NB, 2, BATCH);   // 64 x 2 x 4 = 512 blocks
    chamfer_both<<<grid, 256, 0, stream>>>(pred, targ, wsb, out);
}